// Round 6
// baseline (343.061 us; speedup 1.0000x reference)
//
#include <hip/hip_runtime.h>
#include <math.h>

typedef unsigned short ushort_t;
typedef unsigned short u16x8 __attribute__((ext_vector_type(8)));
typedef unsigned short u16x4 __attribute__((ext_vector_type(4)));
typedef float f32x4 __attribute__((ext_vector_type(4)));

#define THREADS 256
#define ET      32
#define NBASIS  512
#define NBF     128
#define SBD     16
#define MBD     9
#define NTAP    17
#define XE_S    136   // ushort stride; row pitch 272B = 16*17 (16B-aligned)
#define H_S     40    // ushort stride
#define GG_S    136

// d_ws layout: bf16 tables (ushort units), then f32 cgT, then edge intermediates
#define WS_WET    0        // W_edge^T  [n=128][k=128] bf16
#define WS_WG1T   16384    // W_g1^T    [q=32][k=128] bf16
#define WS_WG2T   20480    // W_g2^T    [b*128+n=640][k=32] bf16
#define WS_BF_END 40960    // ushort count
#define WS_CGF_B  81920    // byte offset of f32 cgT [25][256]
#define WS_EDGE_B 107520   // byte offset of edge intermediates

// LDS offsets (float units) -- total 6400 floats = 25.0 KB
#define OFF_XS   0      // 512 (dead after P4)
#define OFF_SH   512    // 512 (dead after P4)
#define OFF_G    1024   // 544 (dead after P1)
#define OFF_JLO  1568   // 32 int
#define OFF_SRC  1600   // 32 int
#define OFF_TGT  1632   // 32 int
#define OFF_HS   1024   // aliases G..TGT exactly: 640 floats = 32*40 ushort (h, written P3)
#define OFF_TPS  1664   // 32*12 (tpm0..8, sum@9, pad)
#define OFF_XE1  2048   // 2176 = 32*136 ushort (xe1; ggS aliases after P3)
#define OFF_GG   2048
#define OFF_XE2  4224   // 2176
#define SMEM_FLOATS 6400

__device__ __forceinline__ float fsigmoid(float x){ return 1.0f/(1.0f + __expf(-x)); }
__device__ __forceinline__ float fsilu(float x){ return x/(1.0f + __expf(-x)); }

__device__ __forceinline__ ushort_t f2bf(float f){
  unsigned int u = __float_as_uint(f);
  u += 0x7FFFu + ((u >> 16) & 1u);
  return (ushort_t)(u >> 16);
}
__device__ __forceinline__ float bf2f(ushort_t h){
  return __uint_as_float(((unsigned int)h) << 16);
}
__device__ __forceinline__ void mfma_bf16(f32x4& d, u16x8 a, u16x8 b){
  // D[m][n] += A[m][k]*B[k][n]; A-frag lane(l): m=l&15,k=(l>>4)*8+j; B-frag: n=l&15,k=(l>>4)*8+j
  asm volatile("v_mfma_f32_16x16x32_bf16 %0, %1, %2, %0" : "+v"(d) : "v"(a), "v"(b));
}

__global__ void prep_weights_kernel(const float* __restrict__ We,
                                    const float* __restrict__ Wg1,
                                    const float* __restrict__ Wg2,
                                    const float* __restrict__ cgm,
                                    const float* __restrict__ cga,
                                    ushort_t* __restrict__ ws,
                                    float* __restrict__ cgF){
  int tid = blockIdx.x * 256 + threadIdx.x;
  if (tid < 16384) {                       // WeT[n][k] = We[k][n]
    int n = tid >> 7, k = tid & 127;
    ws[WS_WET + tid] = f2bf(We[k*128 + n]);
  } else if (tid < 20480) {                // Wg1T[q][k] = Wg1[k][q]
    int r = tid - 16384; int q = r >> 7, k = r & 127;
    ws[tid] = f2bf(Wg1[k*32 + q]);
  } else if (tid < 40960) {                // Wg2T[b*128+n][k] = Wg2[k][b*128+n]
    int r = tid - 20480; int bn = r >> 5, k = r & 31;
    ws[tid] = f2bf(Wg2[k*640 + bn]);
  } else if (tid < 40960 + 6400) {         // cgT f32 [row=k<25][col=i*16+j]
    int r = tid - 40960; int row = r >> 8, col = r & 255;
    cgF[r] = (row < 16) ? cga[col*16 + row] : cgm[col*9 + (row-16)];
  }
}

__global__ __launch_bounds__(THREADS, 4)
void edge_compute_kernel(
    const float* __restrict__ edge_distance,
    const int*   __restrict__ source_element,
    const int*   __restrict__ target_element,
    const float* __restrict__ x_sph,
    const float* __restrict__ edge_sh,
    const float* __restrict__ W_dist,
    const float* __restrict__ b_dist,
    const float* __restrict__ src_emb,
    const float* __restrict__ tgt_emb,
    const float* __restrict__ b_edge,
    const float* __restrict__ b_g1,
    const float* __restrict__ b_g2,
    const ushort_t* __restrict__ wT,
    const float* __restrict__ cgF,
    ushort_t* __restrict__ xe2g,
    ushort_t* __restrict__ ggg,
    float* __restrict__ tpsg,
    int E)
{
  __shared__ float smem[SMEM_FLOATS];
  float* xs_s  = smem + OFF_XS;
  float* sh_s  = smem + OFF_SH;
  float* g_s   = smem + OFF_G;
  int*   jlo_s = (int*)(smem + OFF_JLO);
  int*   src_s = (int*)(smem + OFF_SRC);
  int*   tgt_s = (int*)(smem + OFF_TGT);
  float* tps_s = smem + OFF_TPS;
  ushort_t* xe1 = (ushort_t*)(smem + OFF_XE1);
  ushort_t* xe2 = (ushort_t*)(smem + OFF_XE2);
  ushort_t* hS  = (ushort_t*)(smem + OFF_HS);   // aliases g/jlo/src/tgt (dead after P1)
  ushort_t* ggS = (ushort_t*)(smem + OFF_GG);   // aliases xe1 (dead after P2)

  const int tid  = threadIdx.x;
  const int lane = tid & 63;
  const int w    = tid >> 6;       // 0..3
  const int l16  = lane & 15;
  const int lq   = lane >> 4;      // 0..3
  const int eb   = blockIdx.x * ET;
  const int ne   = min(ET, E - eb);

  // ---------------- P0: stage inputs ----------------
  for (int idx = tid; idx < ET*SBD; idx += THREADS) {
    int e = idx >> 4;
    bool v = (e < ne);
    int gidx = (eb + e)*SBD + (idx & 15);
    xs_s[idx] = v ? x_sph[gidx]   : 0.0f;
    sh_s[idx] = v ? edge_sh[gidx] : 0.0f;
  }
  if (tid < ET) {
    bool v = (tid < ne);
    int ge = eb + min(tid, ne-1);
    src_s[tid] = v ? source_element[ge] : 0;
    tgt_s[tid] = v ? target_element[ge] : 0;
  }
  const float INVD = (float)(NBASIS - 1) / 6.0f;   // 511/6
  for (int idx = tid; idx < ET*NTAP; idx += THREADS) {
    int e = idx / NTAP;
    int t = idx - e*NTAP;
    bool v = (e < ne);
    float d  = v ? edge_distance[eb + e] : 0.0f;
    float jd = d * INVD;
    int jlo  = (int)floorf(jd) - 8;
    int j    = jlo + t;
    float dj = jd - (float)j;
    float g  = (v && j >= 0 && j < NBASIS) ? __expf(-0.5f*dj*dj) : 0.0f;
    g_s[e*NTAP + t] = g;
    if (t == 0) jlo_s[e] = jlo;
  }
  __syncthreads();   // (1)

  // ---------------- P1: x_dist (17 taps) + emb + silu -> xe1 bf16 ------
  {
    const int er = tid >> 5;       // 0..7  -> 4 edges each
    const int cq = tid & 31;       // 0..31 -> 4 channels each
    const int c0 = cq << 2;
    #pragma unroll 1
    for (int i=0;i<4;i++){
      const int e = er*4 + i;
      const float4 bd = *(const float4*)(b_dist + c0);
      float a0=bd.x, a1=bd.y, a2=bd.z, a3=bd.w;
      const int jlo = jlo_s[e];
      #pragma unroll 4
      for (int t=0; t<NTAP; t++){
        float g = g_s[e*NTAP + t];
        int j = jlo + t;
        j = max(0, min(NBASIS-1, j));
        const float4 wv = *(const float4*)(W_dist + j*NBF + c0);
        a0 += g*wv.x; a1 += g*wv.y; a2 += g*wv.z; a3 += g*wv.w;
      }
      const float4 se = *(const float4*)(src_emb + src_s[e]*NBF + c0);
      const float4 te = *(const float4*)(tgt_emb + tgt_s[e]*NBF + c0);
      u16x4 v;
      v[0] = f2bf(fsilu(a0 + se.x + te.x));
      v[1] = f2bf(fsilu(a1 + se.y + te.y));
      v[2] = f2bf(fsilu(a2 + se.z + te.z));
      v[3] = f2bf(fsilu(a3 + se.w + te.w));
      *(u16x4*)(xe1 + e*XE_S + c0) = v;
    }
  }

  // ------- P4: tensor products, cg f32 rows from ws (contiguous) -------
  {
    const int kk = tid & 31;       // 0..15 = tp_all k, 16..24 = tp_mid k
    const int eg = tid >> 5;       // 0..7
    const float* cgp = cgF + kk*256;
    #pragma unroll 1
    for (int p=0;p<2;p++){
      const int ea = eg*4 + p*2;
      float acc0 = 0.0f, acc1 = 0.0f;
      if (kk < 25) {
        float sh0[16], sh1[16];
        #pragma unroll
        for (int j=0;j<16;j++){ sh0[j]=sh_s[ea*SBD+j]; sh1[j]=sh_s[(ea+1)*SBD+j]; }
        #pragma unroll 2
        for (int i=0;i<16;i++){
          const f32x4 c0v = *(const f32x4*)(cgp + i*16);
          const f32x4 c1v = *(const f32x4*)(cgp + i*16 + 4);
          const f32x4 c2v = *(const f32x4*)(cgp + i*16 + 8);
          const f32x4 c3v = *(const f32x4*)(cgp + i*16 + 12);
          float s0=0.0f, s1=0.0f;
          #pragma unroll
          for (int j=0;j<4;j++){ s0 += sh0[j]*c0v[j];    s1 += sh1[j]*c0v[j]; }
          #pragma unroll
          for (int j=0;j<4;j++){ s0 += sh0[4+j]*c1v[j];  s1 += sh1[4+j]*c1v[j]; }
          #pragma unroll
          for (int j=0;j<4;j++){ s0 += sh0[8+j]*c2v[j];  s1 += sh1[8+j]*c2v[j]; }
          #pragma unroll
          for (int j=0;j<4;j++){ s0 += sh0[12+j]*c3v[j]; s1 += sh1[12+j]*c3v[j]; }
          acc0 += xs_s[ea*SBD+i]*s0;
          acc1 += xs_s[(ea+1)*SBD+i]*s1;
        }
      }
      if (kk < 16) {
        float t00 = acc0, t01 = acc1;
        float s0v = acc0, s1v = acc1;
        #pragma unroll
        for (int m=1;m<16;m<<=1){ s0v += __shfl_xor(s0v,m); s1v += __shfl_xor(s1v,m); }
        if (kk == 0) {
          tps_s[ea*12 + 9]     = fsigmoid(t00)*s0v;  // silu(t0)+sigmoid(t0)*sum(rest)
          tps_s[(ea+1)*12 + 9] = fsigmoid(t01)*s1v;
        }
      } else if (kk < 25) {
        tps_s[ea*12     + kk-16] = acc0;
        tps_s[(ea+1)*12 + kk-16] = acc1;
      }
    }
  }
  __syncthreads();   // (2) publishes xe1, tps

  // ---------------- P2: xe2 = silu(xe1 @ W_edge + b_edge), MFMA --------
  {
    const int m0 = (w & 1) * 16;
    const int nb = (w >> 1) * 64;
    u16x8 af[4];
    #pragma unroll
    for (int kk=0; kk<4; kk++)
      af[kk] = *(const u16x8*)(xe1 + (m0 + l16)*XE_S + kk*32 + lq*8);
    #pragma unroll 1
    for (int t=0;t<4;t++){
      f32x4 acc = (f32x4){0.f,0.f,0.f,0.f};
      #pragma unroll
      for (int kk=0; kk<4; kk++){
        const u16x8 b = *(const u16x8*)(wT + WS_WET + (nb + t*16 + l16)*128 + kk*32 + lq*8);
        mfma_bf16(acc, af[kk], b);
      }
      const int n = nb + t*16 + l16;
      const float be = b_edge[n];
      #pragma unroll
      for (int j=0;j<4;j++){
        const int m = m0 + lq*4 + j;
        xe2[m*XE_S + n] = f2bf(fsilu(acc[j] + be));
      }
    }
  }
  __syncthreads();   // (3) publishes xe2 (xe1 dead)

  // ---------------- P3: h = relu(xe2 @ W_g1 + b_g1), MFMA --------------
  {
    const int m0 = (w & 1) * 16;
    const int n0 = (w >> 1) * 16;
    f32x4 acc3 = (f32x4){0.f,0.f,0.f,0.f};
    #pragma unroll
    for (int kk=0; kk<4; kk++){
      const u16x8 a = *(const u16x8*)(xe2 + (m0 + l16)*XE_S + kk*32 + lq*8);
      const u16x8 b = *(const u16x8*)(wT + WS_WG1T + (n0 + l16)*128 + kk*32 + lq*8);
      mfma_bf16(acc3, a, b);
    }
    const float bg = b_g1[n0 + l16];
    #pragma unroll
    for (int j=0;j<4;j++){
      const int m = m0 + lq*4 + j;
      hS[m*H_S + n0 + l16] = f2bf(fmaxf(acc3[j] + bg, 0.0f));
    }
  }
  __syncthreads();   // (4) publishes h

  // ------- P5: gate branch-0 via MFMA x5 per 16-ch tile -> ggS bf16 ----
  {
    const int m0 = (w & 1) * 16;
    const int cb = (w >> 1) * 64;
    const u16x8 ah = *(const u16x8*)(hS + (m0 + l16)*H_S + lq*8);
    #pragma unroll 1
    for (int t=0;t<4;t++){
      const int c = cb + t*16 + l16;
      float sden4[4] = {0.f,0.f,0.f,0.f};
      float z0e4[4];
      #pragma unroll
      for (int b=0;b<5;b++){
        const u16x8 bw = *(const u16x8*)(wT + WS_WG2T + (b*128 + c)*32 + lq*8);
        f32x4 z = (f32x4){0.f,0.f,0.f,0.f};
        mfma_bf16(z, ah, bw);
        const float bg = b_g2[b*128 + c];
        #pragma unroll
        for (int j=0;j<4;j++){
          float ez = __expf(z[j] + bg);
          sden4[j] += ez;
          if (b == 0) z0e4[j] = ez;
        }
      }
      #pragma unroll
      for (int j=0;j<4;j++){
        const int m = m0 + lq*4 + j;
        ggS[m*GG_S + c] = f2bf(z0e4[j] / sden4[j]);
      }
    }
  }
  __syncthreads();   // (5) publishes ggS

  // ------- P6-lite: dump intermediates to ws (coalesced) ---------------
  // xe2 + gg: 32 rows x 16 u16x8-chunks each
  #pragma unroll 1
  for (int ch = tid; ch < ET*16; ch += THREADS){
    const int row = ch >> 4;
    const int c8  = (ch & 15) << 3;
    if (row < ne){
      *(u16x8*)(xe2g + (size_t)(eb+row)*NBF + c8) = *(const u16x8*)(xe2 + row*XE_S + c8);
      *(u16x8*)(ggg  + (size_t)(eb+row)*NBF + c8) = *(const u16x8*)(ggS + row*GG_S + c8);
    }
  }
  for (int idx = tid; idx < ET*12; idx += THREADS){
    if (idx < ne*12) tpsg[(size_t)eb*12 + idx] = tps_s[idx];
  }
}

// ---------------- Kernel B: pure expand/stream ----------------
__global__ __launch_bounds__(256, 4)
void expand_kernel(const ushort_t* __restrict__ xe2g,
                   const ushort_t* __restrict__ ggg,
                   const float*    __restrict__ tpsg,
                   const float*    __restrict__ W_path,
                   float* __restrict__ out,
                   int E)
{
  const int j = blockIdx.x * 256 + threadIdx.x;
  const int e = j >> 5;
  if (e >= E) return;
  const int c0 = (j & 31) << 2;

  const u16x4 xv = *(const u16x4*)(xe2g + (size_t)e*NBF + c0);
  const u16x4 gv = *(const u16x4*)(ggg  + (size_t)e*NBF + c0);
  const f32x4 t0 = *(const f32x4*)(tpsg + (size_t)e*12);
  const f32x4 t1 = *(const f32x4*)(tpsg + (size_t)e*12 + 4);
  const f32x4 t2 = *(const f32x4*)(tpsg + (size_t)e*12 + 8);
  const f32x4 wp0 = *(const f32x4*)(W_path + c0);
  const f32x4 wp1 = *(const f32x4*)(W_path + 128 + c0);
  const f32x4 wp2 = *(const f32x4*)(W_path + 256 + c0);

  const float sum = t2[1];
  f32x4 base, gg, s0, gw1, gw2;
  #pragma unroll
  for (int q=0;q<4;q++){
    base[q] = bf2f(xv[q]) + sum;
    s0[q]   = t0[0] * wp0[q];
    gg[q]   = fsigmoid(s0[q]) * bf2f(gv[q]);
    gw1[q]  = wp1[q] * gg[q];
    gw2[q]  = wp2[q] * gg[q];
  }
  float* op = out + (size_t)e * (MBD*NBF) + c0;
  f32x4 o;
  #pragma unroll
  for (int q=0;q<4;q++) o[q] = s0[q]*gg[q] + base[q];
  *(f32x4*)op = o;
  const float tk[8] = {t0[1],t0[2],t0[3],t1[0],t1[1],t1[2],t1[3],t2[0]};
  #pragma unroll
  for (int k=1;k<MBD;k++){
    const f32x4 gw = (k < 4) ? gw1 : gw2;
    #pragma unroll
    for (int q=0;q<4;q++) o[q] = tk[k-1]*gw[q] + base[q];
    *(f32x4*)(op + k*NBF) = o;
  }
}

extern "C" void kernel_launch(void* const* d_in, const int* in_sizes, int n_in,
                              void* d_out, int out_size, void* d_ws, size_t ws_size,
                              hipStream_t stream) {
  const float* edge_distance  = (const float*)d_in[0];
  const int*   source_element = (const int*)  d_in[1];
  const int*   target_element = (const int*)  d_in[2];
  const float* x_sph   = (const float*)d_in[3];
  const float* edge_sh = (const float*)d_in[4];
  const float* W_dist  = (const float*)d_in[5];
  const float* b_dist  = (const float*)d_in[6];
  const float* src_emb = (const float*)d_in[7];
  const float* tgt_emb = (const float*)d_in[8];
  const float* W_edge  = (const float*)d_in[9];
  const float* b_edge  = (const float*)d_in[10];
  const float* W_g1    = (const float*)d_in[11];
  const float* b_g1    = (const float*)d_in[12];
  const float* W_g2    = (const float*)d_in[13];
  const float* b_g2    = (const float*)d_in[14];
  const float* cg_mid  = (const float*)d_in[15];
  const float* cg_all  = (const float*)d_in[16];
  const float* W_path  = (const float*)d_in[17];
  float* out = (float*)d_out;
  const int E = in_sizes[0];

  char* wsb = (char*)d_ws;
  ushort_t* wT   = (ushort_t*)wsb;
  float*    cgF  = (float*)(wsb + WS_CGF_B);
  ushort_t* xe2g = (ushort_t*)(wsb + WS_EDGE_B);
  ushort_t* ggg  = (ushort_t*)(wsb + WS_EDGE_B + (size_t)E*NBF*2);
  float*    tpsg = (float*)   (wsb + WS_EDGE_B + (size_t)E*NBF*4);

  hipLaunchKernelGGL(prep_weights_kernel, dim3((40960 + 6400 + 255)/256), dim3(256), 0, stream,
                     W_edge, W_g1, W_g2, cg_mid, cg_all, wT, cgF);

  const int nblkA = (E + ET - 1) / ET;
  hipLaunchKernelGGL(edge_compute_kernel, dim3(nblkA), dim3(THREADS), 0, stream,
                     edge_distance, source_element, target_element, x_sph, edge_sh,
                     W_dist, b_dist, src_emb, tgt_emb, b_edge,
                     b_g1, b_g2, wT, cgF, xe2g, ggg, tpsg, E);

  const long long jobs = (long long)E * 32;
  const int nblkB = (int)((jobs + 255) / 256);
  hipLaunchKernelGGL(expand_kernel, dim3(nblkB), dim3(256), 0, stream,
                     xe2g, ggg, tpsg, W_path, out, E);
}